// Round 9
// baseline (396.180 us; speedup 1.0000x reference)
//
#include <hip/hip_runtime.h>
#include <cstdint>
#include <cstddef>

#define DM 1024
#define NH 16
#define DH 64
#define SEQ 2048
#define NB 2
#define WIN2 256   // WINDOW/2
#define QBLK 64
#define KBLK 128

typedef float f32x4 __attribute__((ext_vector_type(4)));
typedef __bf16 bf16x8 __attribute__((ext_vector_type(8)));
typedef unsigned short u16x8 __attribute__((ext_vector_type(8)));
typedef unsigned short u16x4 __attribute__((ext_vector_type(4)));
typedef float f32x4v __attribute__((ext_vector_type(4)));

__device__ __forceinline__ unsigned short f2bf(float x) {
  unsigned int u = __float_as_uint(x);
  u += 0x7FFFu + ((u >> 16) & 1u);
  return (unsigned short)(u >> 16);
}
__device__ __forceinline__ float bf2f(unsigned short h) {
  return __uint_as_float(((unsigned int)h) << 16);
}
__device__ __forceinline__ f32x4 mfma_bf16(u16x8 a, u16x8 b, f32x4 c) {
  return __builtin_amdgcn_mfma_f32_16x16x32_bf16(
      __builtin_bit_cast(bf16x8, a), __builtin_bit_cast(bf16x8, b), c, 0, 0, 0);
}

// ---------------- prep: split hidden fp32 -> hi/lo bf16 ----------------
__global__ __launch_bounds__(256) void hsplit_kernel(
    const float* __restrict__ x, unsigned short* __restrict__ hi,
    unsigned short* __restrict__ lo, int n4) {
  int i = blockIdx.x * 256 + threadIdx.x;
  int stride = gridDim.x * 256;
  for (; i < n4; i += stride) {
    f32x4v v = *(const f32x4v*)(x + (size_t)i * 4);
    u16x4 h, l;
#pragma unroll
    for (int j = 0; j < 4; ++j) {
      h[j] = f2bf(v[j]);
      l[j] = f2bf(v[j] - bf2f(h[j]));
    }
    *(u16x4*)(hi + (size_t)i * 4) = h;
    *(u16x4*)(lo + (size_t)i * 4) = l;
  }
}

// ------------- prep: weights fp32 [k][n] -> transposed hi/lo bf16 [n][k] -------------
__global__ __launch_bounds__(256) void wsplit_kernel(
    const float* __restrict__ W0, const float* __restrict__ W1,
    const float* __restrict__ W2, const float* __restrict__ W3,
    unsigned short* __restrict__ pwhi, unsigned short* __restrict__ pwlo) {
  __shared__ float tile[32][33];
  const float* W = blockIdx.z == 0 ? W0 : blockIdx.z == 1 ? W1 : blockIdx.z == 2 ? W2 : W3;
  unsigned short* ohi = pwhi + (size_t)blockIdx.z * DM * DM;
  unsigned short* olo = pwlo + (size_t)blockIdx.z * DM * DM;
  int k0 = blockIdx.y * 32, n0 = blockIdx.x * 32;
  int c = threadIdx.x & 31, r0 = threadIdx.x >> 5;
#pragma unroll
  for (int i = 0; i < 4; ++i) {
    int r = r0 + i * 8;
    tile[r][c] = W[(size_t)(k0 + r) * DM + n0 + c];
  }
  __syncthreads();
#pragma unroll
  for (int i = 0; i < 4; ++i) {
    int nr = r0 + i * 8;
    float v = tile[c][nr];   // = W[k0+c][n0+nr]
    unsigned short h = f2bf(v);
    unsigned short l = f2bf(v - bf2f(h));
    ohi[(size_t)(n0 + nr) * DM + k0 + c] = h;
    olo[(size_t)(n0 + nr) * DM + k0 + c] = l;
  }
}

// ---------------- split bf16 GEMM: C = A @ W (+bias) ----------------
// A: [4096][1024] pre-split hi/lo bf16, row-major (k contiguous)
// W: pre-transposed hi/lo bf16 [n][k]
// MODE 0: epilogue scatter-> Q/K/V bf16 [B,H,S,DH] (wz = blockIdx.z picks weight/out)
// MODE 1: epilogue -> fp32 out + bias (uses weight index 3)
template <int MODE>
__global__ __launch_bounds__(256) void gemm_split_kernel(
    const unsigned short* __restrict__ Ahi, const unsigned short* __restrict__ Alo,
    const unsigned short* __restrict__ Wthi, const unsigned short* __restrict__ Wtlo,
    unsigned short* __restrict__ Qo, unsigned short* __restrict__ Ko,
    unsigned short* __restrict__ Vo, float* __restrict__ Out,
    const float* __restrict__ bias) {
  __shared__ alignas(16) unsigned short sAh[128][40];
  __shared__ alignas(16) unsigned short sAl[128][40];
  __shared__ alignas(16) unsigned short sBh[128][40];
  __shared__ alignas(16) unsigned short sBl[128][40];
  const int t = threadIdx.x;
  const int lane = t & 63, wave = t >> 6;
  const int l15 = lane & 15, l4 = lane >> 4;
  const int wr = wave >> 1, wc = wave & 1;
  const int mB = blockIdx.y, nB = blockIdx.x, wz = blockIdx.z;
  const unsigned short* Bh = Wthi + (size_t)(MODE == 0 ? wz : 3) * DM * DM;
  const unsigned short* Bl = Wtlo + (size_t)(MODE == 0 ? wz : 3) * DM * DM;
  f32x4 acc[4][4];
#pragma unroll
  for (int m = 0; m < 4; ++m)
#pragma unroll
    for (int n = 0; n < 4; ++n) acc[m][n] = (f32x4)0.0f;

  for (int kt = 0; kt < DM / 32; ++kt) {
    __syncthreads();
#pragma unroll
    for (int i = 0; i < 2; ++i) {
      int slot = t + i * 256;           // 0..511
      int row = slot >> 2, c8 = slot & 3;
      size_t ga = (size_t)(mB * 128 + row) * DM + kt * 32 + c8 * 8;
      *(u16x8*)&sAh[row][c8 * 8] = *(const u16x8*)(Ahi + ga);
      *(u16x8*)&sAl[row][c8 * 8] = *(const u16x8*)(Alo + ga);
      size_t gb = (size_t)(nB * 128 + row) * DM + kt * 32 + c8 * 8;
      *(u16x8*)&sBh[row][c8 * 8] = *(const u16x8*)(Bh + gb);
      *(u16x8*)&sBl[row][c8 * 8] = *(const u16x8*)(Bl + gb);
    }
    __syncthreads();
    u16x8 ah[4], al[4];
#pragma unroll
    for (int m = 0; m < 4; ++m) {
      ah[m] = *(const u16x8*)&sAh[wr * 64 + m * 16 + l15][8 * l4];
      al[m] = *(const u16x8*)&sAl[wr * 64 + m * 16 + l15][8 * l4];
    }
#pragma unroll
    for (int n = 0; n < 4; ++n) {
      u16x8 bh = *(const u16x8*)&sBh[wc * 64 + n * 16 + l15][8 * l4];
      u16x8 bl = *(const u16x8*)&sBl[wc * 64 + n * 16 + l15][8 * l4];
#pragma unroll
      for (int m = 0; m < 4; ++m) {
        acc[m][n] = mfma_bf16(ah[m], bh, acc[m][n]);
        acc[m][n] = mfma_bf16(ah[m], bl, acc[m][n]);
        acc[m][n] = mfma_bf16(al[m], bh, acc[m][n]);
      }
    }
  }
#pragma unroll
  for (int m = 0; m < 4; ++m)
#pragma unroll
    for (int n = 0; n < 4; ++n)
#pragma unroll
      for (int r = 0; r < 4; ++r) {
        int rg = mB * 128 + wr * 64 + m * 16 + l4 * 4 + r;
        int cg = nB * 128 + wc * 64 + n * 16 + l15;
        float v = acc[m][n][r];
        if constexpr (MODE == 0) {
          int b = rg >> 11, s = rg & 2047, h = cg >> 6, d = cg & 63;
          size_t o = ((size_t)((b << 4) + h) * SEQ + s) * DH + d;
          unsigned short bf = f2bf(v);
          if (wz == 0) Qo[o] = bf;
          else if (wz == 1) Ko[o] = bf;
          else Vo[o] = bf;
        } else {
          Out[(size_t)rg * DM + cg] = v + bias[cg];
        }
      }
}

// ---------------- windowed flash attention ----------------
// Q/K/V: bf16 [B,H,S,DH]. Output: hi/lo bf16 split, token-major [B*S][DM].
__global__ __launch_bounds__(256) void attn_kernel(
    const unsigned short* __restrict__ Qg, const unsigned short* __restrict__ Kg,
    const unsigned short* __restrict__ Vg, unsigned short* __restrict__ Ohi,
    unsigned short* __restrict__ Olo) {
  __shared__ alignas(16) unsigned short sQ[QBLK][72];
  __shared__ alignas(16) unsigned short sK[KBLK][72];
  __shared__ alignas(16) unsigned short sVt[DH][136];
  __shared__ alignas(16) unsigned short sP[QBLK][136];
  const int t = threadIdx.x;
  const int lane = t & 63, wave = t >> 6;
  const int l15 = lane & 15, l4 = lane >> 4;
  const int qb = blockIdx.x, h = blockIdx.y, b = blockIdx.z;
  const int q0 = qb * QBLK;
  const size_t hb = ((size_t)b * NH + h) * SEQ * DH;
  const int wrow = wave * 16;

#pragma unroll
  for (int i = 0; i < 2; ++i) {
    int slot = t + i * 256;               // 512 slots: 64 rows x 8
    int row = slot >> 3, c8 = slot & 7;
    *(u16x8*)&sQ[row][c8 * 8] =
        *(const u16x8*)(Qg + hb + (size_t)(q0 + row) * DH + c8 * 8);
  }

  f32x4 oacc[4];
#pragma unroll
  for (int n = 0; n < 4; ++n) oacc[n] = (f32x4)0.0f;
  float mrun[4], lrun[4];
#pragma unroll
  for (int r = 0; r < 4; ++r) { mrun[r] = -3.0e38f; lrun[r] = 0.0f; }

  const int tlo = (q0 >= WIN2) ? ((q0 - WIN2) >> 7) : 0;
  int thi = (q0 + QBLK - 1 + WIN2) >> 7;
  if (thi > SEQ / KBLK - 1) thi = SEQ / KBLK - 1;

  for (int tt = 0; tt < SEQ / KBLK; ++tt) {
    bool visit = (tt == 0) || (qb == 0) || (tt >= tlo && tt <= thi);
    if (!visit) continue;
    __syncthreads();
    // stage K [128][64]
#pragma unroll
    for (int i = 0; i < 4; ++i) {
      int slot = t + i * 256;
      int row = slot >> 3, c8 = slot & 7;
      *(u16x8*)&sK[row][c8 * 8] =
          *(const u16x8*)(Kg + hb + (size_t)(tt * KBLK + row) * DH + c8 * 8);
    }
    // stage V transposed -> sVt[d][j]
#pragma unroll
    for (int i = 0; i < 4; ++i) {
      int slot = t + i * 256;
      int row = slot >> 3, c8 = slot & 7;
      u16x8 v = *(const u16x8*)(Vg + hb + (size_t)(tt * KBLK + row) * DH + c8 * 8);
#pragma unroll
      for (int jj = 0; jj < 8; ++jj) sVt[c8 * 8 + jj][row] = v[jj];
    }
    __syncthreads();

    // QK^T
    f32x4 sc[8];
#pragma unroll
    for (int n = 0; n < 8; ++n) sc[n] = (f32x4)0.0f;
#pragma unroll
    for (int ks = 0; ks < 2; ++ks) {
      u16x8 qa = *(const u16x8*)&sQ[wrow + l15][ks * 32 + 8 * l4];
#pragma unroll
      for (int n = 0; n < 8; ++n) {
        u16x8 kb = *(const u16x8*)&sK[n * 16 + l15][ks * 32 + 8 * l4];
        sc[n] = mfma_bf16(qa, kb, sc[n]);
      }
    }
    // scale + mask + row max
    const int iabs_base = q0 + wrow + l4 * 4;
    float tmax[4];
#pragma unroll
    for (int r = 0; r < 4; ++r) tmax[r] = -3.0e38f;
#pragma unroll
    for (int n = 0; n < 8; ++n) {
      int jabs = tt * KBLK + n * 16 + l15;
#pragma unroll
      for (int r = 0; r < 4; ++r) {
        int iabs = iabs_base + r;
        float s = sc[n][r] * 0.125f;
        int dd = iabs - jabs; if (dd < 0) dd = -dd;
        bool ok = (dd <= WIN2) || (iabs < 1) || (jabs < 1);
        s = ok ? s : -1.0e30f;
        sc[n][r] = s;
        tmax[r] = fmaxf(tmax[r], s);
      }
    }
#pragma unroll
    for (int r = 0; r < 4; ++r) {
      float v = tmax[r];
      v = fmaxf(v, __shfl_xor(v, 1));
      v = fmaxf(v, __shfl_xor(v, 2));
      v = fmaxf(v, __shfl_xor(v, 4));
      v = fmaxf(v, __shfl_xor(v, 8));
      tmax[r] = v;
    }
    float scl[4], tsum[4];
#pragma unroll
    for (int r = 0; r < 4; ++r) {
      float mnew = fmaxf(mrun[r], tmax[r]);
      scl[r] = __expf(mrun[r] - mnew);
      mrun[r] = mnew;
      tsum[r] = 0.0f;
    }
#pragma unroll
    for (int n = 0; n < 8; ++n) {
#pragma unroll
      for (int r = 0; r < 4; ++r) {
        float p = __expf(sc[n][r] - mrun[r]);
        sc[n][r] = p;
        tsum[r] += p;
      }
    }
#pragma unroll
    for (int r = 0; r < 4; ++r) {
      float v = tsum[r];
      v += __shfl_xor(v, 1);
      v += __shfl_xor(v, 2);
      v += __shfl_xor(v, 4);
      v += __shfl_xor(v, 8);
      lrun[r] = lrun[r] * scl[r] + v;
    }
#pragma unroll
    for (int n = 0; n < 4; ++n)
#pragma unroll
      for (int r = 0; r < 4; ++r) oacc[n][r] *= scl[r];
    // write P (bf16)
#pragma unroll
    for (int n = 0; n < 8; ++n)
#pragma unroll
      for (int r = 0; r < 4; ++r)
        sP[wrow + l4 * 4 + r][n * 16 + l15] = f2bf(sc[n][r]);
    __syncthreads();
    // PV
#pragma unroll
    for (int kt4 = 0; kt4 < 4; ++kt4) {
      u16x8 pa = *(const u16x8*)&sP[wrow + l15][kt4 * 32 + 8 * l4];
#pragma unroll
      for (int n = 0; n < 4; ++n) {
        u16x8 vb = *(const u16x8*)&sVt[n * 16 + l15][kt4 * 32 + 8 * l4];
        oacc[n] = mfma_bf16(pa, vb, oacc[n]);
      }
    }
  }
  // epilogue: normalize + split hi/lo, token-major [B*S][DM]
#pragma unroll
  for (int n = 0; n < 4; ++n)
#pragma unroll
    for (int r = 0; r < 4; ++r) {
      int srow = q0 + wrow + l4 * 4 + r;
      int d = n * 16 + l15;
      float v = oacc[n][r] / lrun[r];
      unsigned short uhi = f2bf(v);
      unsigned short ulo = f2bf(v - bf2f(uhi));
      size_t o = ((size_t)b * SEQ + srow) * DM + h * DH + d;
      Ohi[o] = uhi;
      Olo[o] = ulo;
    }
}

extern "C" void kernel_launch(void* const* d_in, const int* in_sizes, int n_in,
                              void* d_out, int out_size, void* d_ws, size_t ws_size,
                              hipStream_t stream) {
  const float* hid = (const float*)d_in[0];
  const float* Wq = (const float*)d_in[1];
  const float* Wk = (const float*)d_in[2];
  const float* Wv = (const float*)d_in[3];
  const float* Wo = (const float*)d_in[4];
  const float* bo = (const float*)d_in[5];
  float* out = (float*)d_out;

  const size_t HS = (size_t)NB * SEQ * DM;  // 4096*1024
  unsigned short* hhi = (unsigned short*)d_ws;
  unsigned short* hlo = hhi + HS;
  unsigned short* wthi = hlo + HS;                       // [4][1024][1024]
  unsigned short* wtlo = wthi + (size_t)4 * DM * DM;
  unsigned short* Qb = wtlo + (size_t)4 * DM * DM;       // [B,H,S,DH]
  unsigned short* Kb = Qb + HS;
  unsigned short* Vb = Kb + HS;
  // attention output (pre-split) reuses the hidden-split buffers
  unsigned short* attn_hi = hhi;
  unsigned short* attn_lo = hlo;

  hsplit_kernel<<<dim3(2048), dim3(256), 0, stream>>>(hid, hhi, hlo, (int)(HS / 4));
  wsplit_kernel<<<dim3(32, 32, 4), dim3(256), 0, stream>>>(Wq, Wk, Wv, Wo, wthi, wtlo);
  gemm_split_kernel<0><<<dim3(8, 32, 3), dim3(256), 0, stream>>>(
      hhi, hlo, wthi, wtlo, Qb, Kb, Vb, nullptr, nullptr);
  attn_kernel<<<dim3(SEQ / QBLK, NH, NB), dim3(256), 0, stream>>>(
      Qb, Kb, Vb, attn_hi, attn_lo);
  gemm_split_kernel<1><<<dim3(8, 32, 1), dim3(256), 0, stream>>>(
      attn_hi, attn_lo, wthi, wtlo, nullptr, nullptr, nullptr, out, bo);
}

// Round 10
// 340.370 us; speedup vs baseline: 1.1640x; 1.1640x over previous
//
#include <hip/hip_runtime.h>
#include <cstdint>
#include <cstddef>

#define DM 1024
#define NH 16
#define DH 64
#define SEQ 2048
#define NB 2
#define WIN2 256   // WINDOW/2
#define QBLK 64
#define KBLK 128

typedef float f32x4 __attribute__((ext_vector_type(4)));
typedef __bf16 bf16x8 __attribute__((ext_vector_type(8)));
typedef unsigned short u16x8 __attribute__((ext_vector_type(8)));
typedef unsigned short u16x4 __attribute__((ext_vector_type(4)));
typedef float f32x4v __attribute__((ext_vector_type(4)));

__device__ __forceinline__ unsigned short f2bf(float x) {
  unsigned int u = __float_as_uint(x);
  u += 0x7FFFu + ((u >> 16) & 1u);
  return (unsigned short)(u >> 16);
}
__device__ __forceinline__ float bf2f(unsigned short h) {
  return __uint_as_float(((unsigned int)h) << 16);
}
__device__ __forceinline__ f32x4 mfma_bf16(u16x8 a, u16x8 b, f32x4 c) {
  return __builtin_amdgcn_mfma_f32_16x16x32_bf16(
      __builtin_bit_cast(bf16x8, a), __builtin_bit_cast(bf16x8, b), c, 0, 0, 0);
}

// ---------------- prep: split hidden fp32 -> hi/lo bf16 ----------------
__global__ __launch_bounds__(256) void hsplit_kernel(
    const float* __restrict__ x, unsigned short* __restrict__ hi,
    unsigned short* __restrict__ lo, int n4) {
  int i = blockIdx.x * 256 + threadIdx.x;
  int stride = gridDim.x * 256;
  for (; i < n4; i += stride) {
    f32x4v v = *(const f32x4v*)(x + (size_t)i * 4);
    u16x4 h, l;
#pragma unroll
    for (int j = 0; j < 4; ++j) {
      h[j] = f2bf(v[j]);
      l[j] = f2bf(v[j] - bf2f(h[j]));
    }
    *(u16x4*)(hi + (size_t)i * 4) = h;
    *(u16x4*)(lo + (size_t)i * 4) = l;
  }
}

// ------------- prep: weights fp32 [k][n] -> transposed hi/lo bf16 [n][k] -------------
__global__ __launch_bounds__(256) void wsplit_kernel(
    const float* __restrict__ W0, const float* __restrict__ W1,
    const float* __restrict__ W2, const float* __restrict__ W3,
    unsigned short* __restrict__ pwhi, unsigned short* __restrict__ pwlo) {
  __shared__ float tile[32][33];
  const float* W = blockIdx.z == 0 ? W0 : blockIdx.z == 1 ? W1 : blockIdx.z == 2 ? W2 : W3;
  unsigned short* ohi = pwhi + (size_t)blockIdx.z * DM * DM;
  unsigned short* olo = pwlo + (size_t)blockIdx.z * DM * DM;
  int k0 = blockIdx.y * 32, n0 = blockIdx.x * 32;
  int c = threadIdx.x & 31, r0 = threadIdx.x >> 5;
#pragma unroll
  for (int i = 0; i < 4; ++i) {
    int r = r0 + i * 8;
    tile[r][c] = W[(size_t)(k0 + r) * DM + n0 + c];
  }
  __syncthreads();
#pragma unroll
  for (int i = 0; i < 4; ++i) {
    int nr = r0 + i * 8;
    float v = tile[c][nr];   // = W[k0+c][n0+nr]
    unsigned short h = f2bf(v);
    unsigned short l = f2bf(v - bf2f(h));
    ohi[(size_t)(n0 + nr) * DM + k0 + c] = h;
    olo[(size_t)(n0 + nr) * DM + k0 + c] = l;
  }
}

// ---------------- split bf16 GEMM: C = A @ W (+bias) ----------------
// MODE 0: scatter -> Q/K bf16 [B,H,S,DH]; V is written TRANSPOSED [B,H,DH,S]
// MODE 1: epilogue -> fp32 out + bias (weight index 3)
template <int MODE>
__global__ __launch_bounds__(256) void gemm_split_kernel(
    const unsigned short* __restrict__ Ahi, const unsigned short* __restrict__ Alo,
    const unsigned short* __restrict__ Wthi, const unsigned short* __restrict__ Wtlo,
    unsigned short* __restrict__ Qo, unsigned short* __restrict__ Ko,
    unsigned short* __restrict__ Vo, float* __restrict__ Out,
    const float* __restrict__ bias) {
  __shared__ alignas(16) unsigned short sAh[128][40];
  __shared__ alignas(16) unsigned short sAl[128][40];
  __shared__ alignas(16) unsigned short sBh[128][40];
  __shared__ alignas(16) unsigned short sBl[128][40];
  const int t = threadIdx.x;
  const int lane = t & 63, wave = t >> 6;
  const int l15 = lane & 15, l4 = lane >> 4;
  const int wr = wave >> 1, wc = wave & 1;
  const int mB = blockIdx.y, nB = blockIdx.x, wz = blockIdx.z;
  const unsigned short* Bh = Wthi + (size_t)(MODE == 0 ? wz : 3) * DM * DM;
  const unsigned short* Bl = Wtlo + (size_t)(MODE == 0 ? wz : 3) * DM * DM;
  f32x4 acc[4][4];
#pragma unroll
  for (int m = 0; m < 4; ++m)
#pragma unroll
    for (int n = 0; n < 4; ++n) acc[m][n] = (f32x4)0.0f;

  for (int kt = 0; kt < DM / 32; ++kt) {
    __syncthreads();
#pragma unroll
    for (int i = 0; i < 2; ++i) {
      int slot = t + i * 256;           // 0..511
      int row = slot >> 2, c8 = slot & 3;
      size_t ga = (size_t)(mB * 128 + row) * DM + kt * 32 + c8 * 8;
      *(u16x8*)&sAh[row][c8 * 8] = *(const u16x8*)(Ahi + ga);
      *(u16x8*)&sAl[row][c8 * 8] = *(const u16x8*)(Alo + ga);
      size_t gb = (size_t)(nB * 128 + row) * DM + kt * 32 + c8 * 8;
      *(u16x8*)&sBh[row][c8 * 8] = *(const u16x8*)(Bh + gb);
      *(u16x8*)&sBl[row][c8 * 8] = *(const u16x8*)(Bl + gb);
    }
    __syncthreads();
    u16x8 ah[4], al[4];
#pragma unroll
    for (int m = 0; m < 4; ++m) {
      ah[m] = *(const u16x8*)&sAh[wr * 64 + m * 16 + l15][8 * l4];
      al[m] = *(const u16x8*)&sAl[wr * 64 + m * 16 + l15][8 * l4];
    }
#pragma unroll
    for (int n = 0; n < 4; ++n) {
      u16x8 bh = *(const u16x8*)&sBh[wc * 64 + n * 16 + l15][8 * l4];
      u16x8 bl = *(const u16x8*)&sBl[wc * 64 + n * 16 + l15][8 * l4];
#pragma unroll
      for (int m = 0; m < 4; ++m) {
        acc[m][n] = mfma_bf16(ah[m], bh, acc[m][n]);
        acc[m][n] = mfma_bf16(ah[m], bl, acc[m][n]);
        acc[m][n] = mfma_bf16(al[m], bh, acc[m][n]);
      }
    }
  }
#pragma unroll
  for (int m = 0; m < 4; ++m)
#pragma unroll
    for (int n = 0; n < 4; ++n)
#pragma unroll
      for (int r = 0; r < 4; ++r) {
        int rg = mB * 128 + wr * 64 + m * 16 + l4 * 4 + r;
        int cg = nB * 128 + wc * 64 + n * 16 + l15;
        float v = acc[m][n][r];
        if constexpr (MODE == 0) {
          int b = rg >> 11, s = rg & 2047, h = cg >> 6, d = cg & 63;
          unsigned short bf = f2bf(v);
          if (wz == 0) {
            Qo[((size_t)((b << 4) + h) * SEQ + s) * DH + d] = bf;
          } else if (wz == 1) {
            Ko[((size_t)((b << 4) + h) * SEQ + s) * DH + d] = bf;
          } else {
            // V written TRANSPOSED: [B,H,DH,S]
            Vo[((size_t)((b << 4) + h) * DH + d) * SEQ + s] = bf;
          }
        } else {
          Out[(size_t)rg * DM + cg] = v + bias[cg];
        }
      }
}

// ---------------- windowed flash attention ----------------
// Q/K: bf16 [B,H,S,DH]; Vt: bf16 [B,H,DH,S] (pre-transposed).
// Output: hi/lo bf16 split, token-major [B*S][DM].
__global__ __launch_bounds__(256) void attn_kernel(
    const unsigned short* __restrict__ Qg, const unsigned short* __restrict__ Kg,
    const unsigned short* __restrict__ Vtg, unsigned short* __restrict__ Ohi,
    unsigned short* __restrict__ Olo) {
  __shared__ alignas(16) unsigned short sK[KBLK][72];   // [s][d]
  __shared__ alignas(16) unsigned short sVt[DH][136];   // [d][s-in-tile]
  __shared__ alignas(16) unsigned short sP[QBLK][136];  // wave-local quadrants
  const int t = threadIdx.x;
  const int lane = t & 63, wave = t >> 6;
  const int l15 = lane & 15, l4 = lane >> 4;
  const int qb = blockIdx.x, h = blockIdx.y, b = blockIdx.z;
  const int q0 = qb * QBLK;
  const size_t hb = ((size_t)b * NH + h) * SEQ * DH;   // also == Vt head base
  const int wrow = wave * 16;

  // Q fragments in registers (wave-local rows)
  u16x8 qreg[2];
#pragma unroll
  for (int ks = 0; ks < 2; ++ks)
    qreg[ks] = *(const u16x8*)(Qg + hb + (size_t)(q0 + wrow + l15) * DH + ks * 32 + 8 * l4);

  f32x4 oacc[4];
#pragma unroll
  for (int n = 0; n < 4; ++n) oacc[n] = (f32x4)0.0f;
  float mrun[4], lrun[4];
#pragma unroll
  for (int r = 0; r < 4; ++r) { mrun[r] = -3.0e38f; lrun[r] = 0.0f; }

  const int tlo = (q0 >= WIN2) ? ((q0 - WIN2) >> 7) : 0;
  int thi = (q0 + QBLK - 1 + WIN2) >> 7;
  if (thi > SEQ / KBLK - 1) thi = SEQ / KBLK - 1;

  for (int tt = 0; tt < SEQ / KBLK; ++tt) {
    bool visit = (tt == 0) || (qb == 0) || (tt >= tlo && tt <= thi);
    if (!visit) continue;
    __syncthreads();   // prev PV done before overwriting sK/sVt
    // stage K [128][64] (row-major, vectorized)
#pragma unroll
    for (int i = 0; i < 4; ++i) {
      int slot = t + i * 256;
      int row = slot >> 3, c8 = slot & 7;
      *(u16x8*)&sK[row][c8 * 8] =
          *(const u16x8*)(Kg + hb + (size_t)(tt * KBLK + row) * DH + c8 * 8);
    }
    // stage V^T [64][128] (vectorized copy from global V^T — no scatter)
#pragma unroll
    for (int i = 0; i < 4; ++i) {
      int slot = t + i * 256;
      int d = slot >> 4, c16 = slot & 15;
      *(u16x8*)&sVt[d][c16 * 8] =
          *(const u16x8*)(Vtg + hb + (size_t)d * SEQ + tt * KBLK + c16 * 8);
    }
    __syncthreads();

    // QK^T
    f32x4 sc[8];
#pragma unroll
    for (int n = 0; n < 8; ++n) sc[n] = (f32x4)0.0f;
#pragma unroll
    for (int ks = 0; ks < 2; ++ks) {
#pragma unroll
      for (int n = 0; n < 8; ++n) {
        u16x8 kb = *(const u16x8*)&sK[n * 16 + l15][ks * 32 + 8 * l4];
        sc[n] = mfma_bf16(qreg[ks], kb, sc[n]);
      }
    }
    // scale + mask + row max
    const int iabs_base = q0 + wrow + l4 * 4;
    float tmax[4];
#pragma unroll
    for (int r = 0; r < 4; ++r) tmax[r] = -3.0e38f;
#pragma unroll
    for (int n = 0; n < 8; ++n) {
      int jabs = tt * KBLK + n * 16 + l15;
#pragma unroll
      for (int r = 0; r < 4; ++r) {
        int iabs = iabs_base + r;
        float s = sc[n][r] * 0.125f;
        int dd = iabs - jabs; if (dd < 0) dd = -dd;
        bool ok = (dd <= WIN2) || (iabs < 1) || (jabs < 1);
        s = ok ? s : -1.0e30f;
        sc[n][r] = s;
        tmax[r] = fmaxf(tmax[r], s);
      }
    }
#pragma unroll
    for (int r = 0; r < 4; ++r) {
      float v = tmax[r];
      v = fmaxf(v, __shfl_xor(v, 1));
      v = fmaxf(v, __shfl_xor(v, 2));
      v = fmaxf(v, __shfl_xor(v, 4));
      v = fmaxf(v, __shfl_xor(v, 8));
      tmax[r] = v;
    }
    float scl[4], tsum[4];
#pragma unroll
    for (int r = 0; r < 4; ++r) {
      float mnew = fmaxf(mrun[r], tmax[r]);
      scl[r] = __expf(mrun[r] - mnew);
      mrun[r] = mnew;
      tsum[r] = 0.0f;
    }
#pragma unroll
    for (int n = 0; n < 8; ++n) {
#pragma unroll
      for (int r = 0; r < 4; ++r) {
        float p = __expf(sc[n][r] - mrun[r]);
        sc[n][r] = p;
        tsum[r] += p;
      }
    }
#pragma unroll
    for (int r = 0; r < 4; ++r) {
      float v = tsum[r];
      v += __shfl_xor(v, 1);
      v += __shfl_xor(v, 2);
      v += __shfl_xor(v, 4);
      v += __shfl_xor(v, 8);
      lrun[r] = lrun[r] * scl[r] + v;
    }
#pragma unroll
    for (int n = 0; n < 4; ++n)
#pragma unroll
      for (int r = 0; r < 4; ++r) oacc[n][r] *= scl[r];
    // write P (bf16) — wave-local rows, no barrier needed before PV
#pragma unroll
    for (int n = 0; n < 8; ++n)
#pragma unroll
      for (int r = 0; r < 4; ++r)
        sP[wrow + l4 * 4 + r][n * 16 + l15] = f2bf(sc[n][r]);
    // PV
#pragma unroll
    for (int kt4 = 0; kt4 < 4; ++kt4) {
      u16x8 pa = *(const u16x8*)&sP[wrow + l15][kt4 * 32 + 8 * l4];
#pragma unroll
      for (int n = 0; n < 4; ++n) {
        u16x8 vb = *(const u16x8*)&sVt[n * 16 + l15][kt4 * 32 + 8 * l4];
        oacc[n] = mfma_bf16(pa, vb, oacc[n]);
      }
    }
  }
  // epilogue: normalize + split hi/lo, token-major [B*S][DM]
#pragma unroll
  for (int n = 0; n < 4; ++n)
#pragma unroll
    for (int r = 0; r < 4; ++r) {
      int srow = q0 + wrow + l4 * 4 + r;
      int d = n * 16 + l15;
      float v = oacc[n][r] / lrun[r];
      unsigned short uhi = f2bf(v);
      unsigned short ulo = f2bf(v - bf2f(uhi));
      size_t o = ((size_t)b * SEQ + srow) * DM + h * DH + d;
      Ohi[o] = uhi;
      Olo[o] = ulo;
    }
}

extern "C" void kernel_launch(void* const* d_in, const int* in_sizes, int n_in,
                              void* d_out, int out_size, void* d_ws, size_t ws_size,
                              hipStream_t stream) {
  const float* hid = (const float*)d_in[0];
  const float* Wq = (const float*)d_in[1];
  const float* Wk = (const float*)d_in[2];
  const float* Wv = (const float*)d_in[3];
  const float* Wo = (const float*)d_in[4];
  const float* bo = (const float*)d_in[5];
  float* out = (float*)d_out;

  const size_t HS = (size_t)NB * SEQ * DM;  // 4096*1024
  unsigned short* hhi = (unsigned short*)d_ws;
  unsigned short* hlo = hhi + HS;
  unsigned short* wthi = hlo + HS;                       // [4][1024][1024]
  unsigned short* wtlo = wthi + (size_t)4 * DM * DM;
  unsigned short* Qb = wtlo + (size_t)4 * DM * DM;       // [B,H,S,DH]
  unsigned short* Kb = Qb + HS;                          // [B,H,S,DH]
  unsigned short* Vtb = Kb + HS;                         // [B,H,DH,S] (transposed)
  // attention output (pre-split) reuses the hidden-split buffers
  unsigned short* attn_hi = hhi;
  unsigned short* attn_lo = hlo;

  hsplit_kernel<<<dim3(2048), dim3(256), 0, stream>>>(hid, hhi, hlo, (int)(HS / 4));
  wsplit_kernel<<<dim3(32, 32, 4), dim3(256), 0, stream>>>(Wq, Wk, Wv, Wo, wthi, wtlo);
  gemm_split_kernel<0><<<dim3(8, 32, 3), dim3(256), 0, stream>>>(
      hhi, hlo, wthi, wtlo, Qb, Kb, Vtb, nullptr, nullptr);
  attn_kernel<<<dim3(SEQ / QBLK, NH, NB), dim3(256), 0, stream>>>(
      Qb, Kb, Vtb, attn_hi, attn_lo);
  gemm_split_kernel<1><<<dim3(8, 32, 1), dim3(256), 0, stream>>>(
      attn_hi, attn_lo, wthi, wtlo, nullptr, nullptr, nullptr, out, bo);
}